// Round 1
// baseline (7585.711 us; speedup 1.0000x reference)
//
#include <hip/hip_runtime.h>
#include <math.h>

#define NN    34
#define NFH   18
#define NFREQ 612
#define CH    256
#define CIN   255
#define NB    64
#define HW    32
#define PI2   6.2831853071795864769f

// ---------------- forward FFT stage 1: along w (real -> 18 complex) --------
// x: (B=64, C=256, 32, 32)   U[a][kx][c][b]
__global__ __launch_bounds__(256) void kF1(const float* __restrict__ x, float2* __restrict__ U){
  __shared__ float tc[NFH][HW], ts[NFH][HW];
  int tid = threadIdx.x;
  for (int i = tid; i < NFH*HW; i += 256){
    int kx = i >> 5, w = i & 31;
    float s, c; sincosf(-PI2*(float)(kx*(w+1))/34.f, &s, &c);
    tc[kx][w] = c; ts[kx][w] = s;
  }
  __syncthreads();
  int c = blockIdx.x;
  int a = (blockIdx.y << 2) + (tid >> 6);
  int b = tid & 63;
  const float4* xr = (const float4*)(x + (((size_t)b*CH + c)*HW + a)*HW);
  float xv[HW];
#pragma unroll
  for (int t = 0; t < 8; t++){
    float4 v = xr[t];
    xv[4*t] = v.x; xv[4*t+1] = v.y; xv[4*t+2] = v.z; xv[4*t+3] = v.w;
  }
#pragma unroll 1
  for (int kx = 0; kx < NFH; kx++){
    float re = 0.f, im = 0.f;
#pragma unroll
    for (int w = 0; w < HW; w++){ re += xv[w]*tc[kx][w]; im += xv[w]*ts[kx][w]; }
    U[(((size_t)a*NFH + kx)*CH + c)*NB + b] = make_float2(re, im);
  }
}

// ---------------- forward FFT stage 2: along a (32 -> 34 complex), scale 1/34
// X[f=ky*18+kx][c][b]
__global__ __launch_bounds__(512) void kF2(const float2* __restrict__ U, float2* __restrict__ X){
  __shared__ float pc[NN][HW], ps[NN][HW];
  int tid = threadIdx.x;
  for (int i = tid; i < NN*HW; i += 512){
    int ky = i >> 5, a = i & 31;
    float s, c; sincosf(-PI2*(float)(ky*(a+1))/34.f, &s, &c);
    pc[ky][a] = c*(1.f/34.f); ps[ky][a] = s*(1.f/34.f);
  }
  __syncthreads();
  int kx = blockIdx.x;
  int c  = (blockIdx.y << 3) + (tid >> 6);
  int b  = tid & 63;
  float2 u[HW];
#pragma unroll
  for (int a = 0; a < HW; a++) u[a] = U[(((size_t)a*NFH + kx)*CH + c)*NB + b];
#pragma unroll 1
  for (int ky = 0; ky < NN; ky++){
    float re = 0.f, im = 0.f;
#pragma unroll
    for (int a = 0; a < HW; a++){
      float cc = pc[ky][a], ss = ps[ky][a];
      re += u[a].x*cc - u[a].y*ss;
      im += u[a].x*ss + u[a].y*cc;
    }
    X[(((size_t)ky*NFH + kx)*CH + c)*NB + b] = make_float2(re, im);
  }
}

// ---------------- transpose weight: wT[k][o*255+i] = w[o][i][k] ------------
__global__ __launch_bounds__(256) void kT0(const float* __restrict__ w, float* __restrict__ wT){
  int idx = blockIdx.x*256 + threadIdx.x;
  if (idx >= 9*CH*CIN) return;
  int k = idx / (CH*CIN);
  int r = idx - k*(CH*CIN);
  wT[idx] = w[(size_t)r*9 + k];
}

// ---------------- C2[kk=k1*9+k2][o][p] = sum_i w[o,i,k1]*w[p,i,k2] ---------
__global__ __launch_bounds__(256) void kC(const float* __restrict__ wT, float* __restrict__ C2){
  int kk = blockIdx.x;
  int k1 = kk / 9, k2 = kk - k1*9;
  int to = (blockIdx.y >> 2) << 6, tp = (blockIdx.y & 3) << 6;
  __shared__ float As[64][33], Bs[64][33];
  int tid = threadIdx.x;
  int ty = tid >> 4, tx = tid & 15;
  float acc[4][4] = {};
  const float* Ab = wT + (size_t)k1*CH*CIN;
  const float* Bb = wT + (size_t)k2*CH*CIN;
  for (int i0 = 0; i0 < CIN; i0 += 32){
    for (int idx = tid; idx < 64*32; idx += 256){
      int r = idx >> 5, j = idx & 31;
      int i = i0 + j;
      As[r][j] = (i < CIN) ? Ab[(size_t)(to + r)*CIN + i] : 0.f;
      Bs[r][j] = (i < CIN) ? Bb[(size_t)(tp + r)*CIN + i] : 0.f;
    }
    __syncthreads();
#pragma unroll
    for (int j = 0; j < 32; j++){
      float av[4], bv[4];
#pragma unroll
      for (int d = 0; d < 4; d++){ av[d] = As[ty*4+d][j]; bv[d] = Bs[tx*4+d][j]; }
#pragma unroll
      for (int da = 0; da < 4; da++)
#pragma unroll
        for (int db = 0; db < 4; db++) acc[da][db] += av[da]*bv[db];
    }
    __syncthreads();
  }
  float* Cb = C2 + (size_t)kk*CH*CH;
#pragma unroll
  for (int da = 0; da < 4; da++)
#pragma unroll
    for (int db = 0; db < 4; db++)
      Cb[(size_t)(to + ty*4 + da)*CH + tp + tx*4 + db] = acc[da][db];
}

// ---------------- M[f][o][p] = sum_kk coef(f,kk) * C2[kk][o][p] ------------
// coef = exp(-i*2pi*(ky*da + kx*db)/34)/1156, da=k1/3-k2/3, db=k1%3-k2%3
__global__ __launch_bounds__(64) void kM(const float* __restrict__ C2, float2* __restrict__ M, int cf0, int cF){
  int o  = blockIdx.x;
  int p0 = blockIdx.y << 5;
  int fl = (blockIdx.z << 6) + threadIdx.x;
  bool act = fl < cF;
  int f = act ? (cf0 + fl) : 0;
  int ky = f / NFH, kx = f - ky*NFH;
  float Pc[5], Ps[5], Qc[5], Qs[5];
#pragma unroll
  for (int d = 0; d < 5; d++){
    float s, c;
    sincosf(-PI2*(float)(ky*(d-2))/34.f, &s, &c);
    Pc[d] = c*(1.f/1156.f); Ps[d] = s*(1.f/1156.f);
    sincosf(-PI2*(float)(kx*(d-2))/34.f, &s, &c);
    Qc[d] = c; Qs[d] = s;
  }
  float ax[32] = {}, ay[32] = {};
  const float* Cb = C2 + (size_t)o*CH + p0;
#pragma unroll 1
  for (int k1 = 0; k1 < 9; k1++){
#pragma unroll 1
    for (int k2 = 0; k2 < 9; k2++){
      int da = k1/3 - k2/3 + 2, db = k1%3 - k2%3 + 2;
      float cr = Pc[da]*Qc[db] - Ps[da]*Qs[db];
      float ci = Pc[da]*Qs[db] + Ps[da]*Qc[db];
      const float* crow = Cb + (size_t)(k1*9 + k2)*CH*CH;
#pragma unroll
      for (int j = 0; j < 32; j++){
        float cv = crow[j];
        ax[j] += cv*cr; ay[j] += cv*ci;
      }
    }
  }
  if (act){
    float2* Mr = M + ((size_t)fl*CH + o)*CH + p0;
#pragma unroll
    for (int j = 0; j < 32; j++) Mr[j] = make_float2(ax[j], ay[j]);
  }
}

// ---------------- eps = 1e-5 * trace(M)/255 ; M += eps*I -------------------
__global__ __launch_bounds__(256) void kEps(float2* __restrict__ M, float* __restrict__ eb, int cf0){
  int fi = blockIdx.x;
  float2* Mf = M + (size_t)fi*CH*CH;
  int o = threadIdx.x;
  __shared__ float red[256];
  float d = Mf[(size_t)o*CH + o].x;
  red[o] = d;
  __syncthreads();
  for (int s = 128; s > 0; s >>= 1){ if (o < s) red[o] += red[o+s]; __syncthreads(); }
  float eps = red[0] * (1e-5f/255.f);
  Mf[(size_t)o*CH + o].x = d + eps;
  if (o == 0) eb[cf0 + fi] = eps;
}

// ---------------- blocked in-place Cholesky (lower), also store conj-T upper
__global__ __launch_bounds__(256) void kChol(float2* __restrict__ Mg){
  int fi = blockIdx.x;
  float2* A = Mg + (size_t)fi*CH*CH;
  __shared__ float2 P[256][33];
  int tid = threadIdx.x;
  for (int pb = 0; pb < 8; pb++){
    int c0 = pb << 5, h = CH - c0;
    for (int idx = tid; idx < h*32; idx += 256){
      int r = idx >> 5, j = idx & 31;
      P[r][j] = A[(size_t)(c0+r)*CH + c0 + j];
    }
    __syncthreads();
    for (int k = 0; k < 32; k++){
      float d = sqrtf(fmaxf(P[k][k].x, 1e-20f));
      float inv = 1.f/d;
      __syncthreads();
      for (int i = k+1+tid; i < h; i += 256){ P[i][k].x *= inv; P[i][k].y *= inv; }
      if (tid == 0) P[k][k] = make_float2(d, 0.f);
      __syncthreads();
      for (int j = k+1; j < 32; j++){
        float2 lj = P[j][k];
        for (int i = j+tid; i < h; i += 256){
          float2 li = P[i][k];
          P[i][j].x -= li.x*lj.x + li.y*lj.y;
          P[i][j].y -= li.y*lj.x - li.x*lj.y;
        }
      }
      __syncthreads();
    }
    // write back panel (final L columns) + conj-transposed copy to upper
    for (int idx = tid; idx < h*32; idx += 256){
      int r = idx >> 5, j = idx & 31;
      A[(size_t)(c0+r)*CH + c0 + j] = P[r][j];
    }
    for (int idx = tid; idx < 32*h; idx += 256){
      int j = idx / h, r = idx - j*h;
      if (r > j){
        float2 v = P[r][j];
        A[(size_t)(c0+j)*CH + c0 + r] = make_float2(v.x, -v.y);
      }
    }
    __syncthreads();
    // trailing update: A[i][j] -= sum_k P[i-c0][k]*conj(P[j-c0][k])
    int ty = tid >> 3, tx = tid & 7;
    for (int jb = pb+1; jb < 8; jb++){
      int jc0 = jb << 5;
      for (int i0 = jc0; i0 < CH; i0 += 128){
        if (i0 + ty*4 < CH){
          int rb = i0 - c0 + ty*4;
          int cb = jc0 - c0 + tx*4;
          float2 acc[4][4] = {};
#pragma unroll 4
          for (int k = 0; k < 32; k++){
            float2 av[4], bv[4];
#pragma unroll
            for (int d = 0; d < 4; d++){ av[d] = P[rb+d][k]; bv[d] = P[cb+d][k]; }
#pragma unroll
            for (int da = 0; da < 4; da++)
#pragma unroll
              for (int db = 0; db < 4; db++){
                acc[da][db].x += av[da].x*bv[db].x + av[da].y*bv[db].y;
                acc[da][db].y += av[da].y*bv[db].x - av[da].x*bv[db].y;
              }
          }
#pragma unroll
          for (int da = 0; da < 4; da++){
            int ii = i0 + ty*4 + da;
#pragma unroll
            for (int db = 0; db < 4; db++){
              int jj = jc0 + tx*4 + db;
              if (ii >= jj){
                float2* ap = A + (size_t)ii*CH + jj;
                float2 v = *ap;
                ap->x = v.x - acc[da][db].x;
                ap->y = v.y - acc[da][db].y;
              }
            }
          }
        }
      }
    }
    __syncthreads();
  }
}

// ---------------- solve (M+eps I) S = X, then X <- 2*eps*S - X -------------
// 4 waves; wave wv owns cols [16wv,16wv+16); q = lane>>4 splits the m-sum.
__global__ __launch_bounds__(256) void kSolve(const float2* __restrict__ Lg, float2* __restrict__ X,
                                              const float* __restrict__ eb, int cf0){
  int fi = blockIdx.x;
  int f = cf0 + fi;
  const float2* A = Lg + (size_t)fi*CH*CH;
  float2* Xf = X + (size_t)f*CH*NB;
  __shared__ float2 S[CH][NB];
  __shared__ float2 Lr[4][2][CH];
  int tid = threadIdx.x, wv = tid >> 6, lane = tid & 63;
  int q = lane >> 4, col = (wv << 4) + (lane & 15);
  float2 pre[4];
#pragma unroll
  for (int t = 0; t < 4; t++) pre[t] = A[t*64 + lane];
  int buf = 0;
#pragma unroll 1
  for (int k = 0; k < CH; k++){
#pragma unroll
    for (int t = 0; t < 4; t++) Lr[wv][buf][t*64 + lane] = pre[t];
    if (k < CH-1){
#pragma unroll
      for (int t = 0; t < 4; t++) pre[t] = A[(size_t)(k+1)*CH + t*64 + lane];
    }
    float sx = 0.f, sy = 0.f;
    for (int m = q; m < k; m += 4){
      float2 l = Lr[wv][buf][m];
      float2 v = S[m][col];
      sx += l.x*v.x - l.y*v.y;
      sy += l.x*v.y + l.y*v.x;
    }
    sx += __shfl_xor(sx, 16, 64); sy += __shfl_xor(sy, 16, 64);
    sx += __shfl_xor(sx, 32, 64); sy += __shfl_xor(sy, 32, 64);
    if (q == 0){
      float2 xv = Xf[(size_t)k*NB + col];
      float dinv = 1.f / Lr[wv][buf][k].x;
      S[k][col] = make_float2((xv.x - sx)*dinv, (xv.y - sy)*dinv);
    }
    buf ^= 1;
  }
  // backward: rows of stored upper hold conj(L[m][k]) already
#pragma unroll
  for (int t = 0; t < 4; t++) pre[t] = A[(size_t)(CH-1)*CH + t*64 + lane];
#pragma unroll 1
  for (int k = CH-1; k >= 0; k--){
#pragma unroll
    for (int t = 0; t < 4; t++) Lr[wv][buf][t*64 + lane] = pre[t];
    if (k > 0){
#pragma unroll
      for (int t = 0; t < 4; t++) pre[t] = A[(size_t)(k-1)*CH + t*64 + lane];
    }
    float sx = 0.f, sy = 0.f;
    for (int m = k+1+q; m < CH; m += 4){
      float2 l = Lr[wv][buf][m];
      float2 v = S[m][col];
      sx += l.x*v.x - l.y*v.y;
      sy += l.x*v.y + l.y*v.x;
    }
    sx += __shfl_xor(sx, 16, 64); sy += __shfl_xor(sy, 16, 64);
    sx += __shfl_xor(sx, 32, 64); sy += __shfl_xor(sy, 32, 64);
    if (q == 0){
      float dinv = 1.f / Lr[wv][buf][k].x;
      float2 v = S[k][col];
      S[k][col] = make_float2((v.x - sx)*dinv, (v.y - sy)*dinv);
    }
    buf ^= 1;
  }
  float te = 2.f * eb[f];
  for (int o = q; o < CH; o += 4){
    float2 sv = S[o][col];
    float2 xv = Xf[(size_t)o*NB + col];
    Xf[(size_t)o*NB + col] = make_float2(te*sv.x - xv.x, te*sv.y - xv.y);
  }
}

// ---------------- inverse FFT stage 1: along ky (34 -> rows a=1..32) -------
__global__ __launch_bounds__(512) void kI1(const float2* __restrict__ X, float2* __restrict__ Y){
  __shared__ float pc[HW][NN], ps[HW][NN];
  int tid = threadIdx.x;
  for (int i = tid; i < HW*NN; i += 512){
    int a = i / NN, ky = i - a*NN;
    float s, c; sincosf(PI2*(float)(ky*(a+1))/34.f, &s, &c);
    pc[a][ky] = c; ps[a][ky] = s;
  }
  __syncthreads();
  int kx = blockIdx.x;
  int cc = (blockIdx.y << 3) + (tid >> 6);
  int b = tid & 63;
  float2 z[NN];
#pragma unroll
  for (int ky = 0; ky < NN; ky++) z[ky] = X[(((size_t)ky*NFH + kx)*CH + cc)*NB + b];
#pragma unroll 1
  for (int a = 0; a < HW; a++){
    float re = 0.f, im = 0.f;
#pragma unroll
    for (int ky = 0; ky < NN; ky++){
      float co = pc[a][ky], si = ps[a][ky];
      re += z[ky].x*co - z[ky].y*si;
      im += z[ky].x*si + z[ky].y*co;
    }
    Y[(((size_t)a*NFH + kx)*CH + cc)*NB + b] = make_float2(re, im);
  }
}

// ---------------- inverse FFT stage 2: along kx (18 -> real w=1..32) + bias
__global__ __launch_bounds__(256) void kI2(const float2* __restrict__ Y, const float* __restrict__ bias,
                                           float* __restrict__ out){
  __shared__ float tc[NFH][HW], tsn[NFH][HW];
  int tid = threadIdx.x;
  for (int i = tid; i < NFH*HW; i += 256){
    int kx = i >> 5, w = i & 31;
    float wt = (kx == 0 || kx == 17) ? (1.f/34.f) : (2.f/34.f);
    float s, c; sincosf(PI2*(float)(kx*(w+1))/34.f, &s, &c);
    tc[kx][w] = wt*c; tsn[kx][w] = wt*s;
  }
  __syncthreads();
  int cc = blockIdx.x;
  int a = (blockIdx.y << 2) + (tid >> 6);
  int b = tid & 63;
  float2 yv[NFH];
#pragma unroll
  for (int kx = 0; kx < NFH; kx++) yv[kx] = Y[(((size_t)a*NFH + kx)*CH + cc)*NB + b];
  float bi = bias[cc];
  float ov[HW];
#pragma unroll
  for (int w = 0; w < HW; w++){
    float acc = bi;
#pragma unroll
    for (int kx = 0; kx < NFH; kx++)
      acc += yv[kx].x*tc[kx][w] - yv[kx].y*tsn[kx][w];
    ov[w] = acc;
  }
  float4* op = (float4*)(out + (((size_t)b*CH + cc)*HW + a)*HW);
#pragma unroll
  for (int t = 0; t < 8; t++) op[t] = make_float4(ov[4*t], ov[4*t+1], ov[4*t+2], ov[4*t+3]);
}

extern "C" void kernel_launch(void* const* d_in, const int* in_sizes, int n_in,
                              void* d_out, int out_size, void* d_ws, size_t ws_size,
                              hipStream_t stream){
  (void)in_sizes; (void)n_in; (void)out_size;
  const float* x    = (const float*)d_in[0];
  const float* w    = (const float*)d_in[1];
  const float* bias = (const float*)d_in[2];
  float* out = (float*)d_out;
  char* ws = (char*)d_ws;

  const size_t X_BYTES  = (size_t)NFREQ*CH*NB*sizeof(float2);   // 80.2 MB
  const size_t WT_BYTES = (size_t)9*CH*CIN*sizeof(float);       // 2.35 MB
  const size_t C_BYTES  = (size_t)81*CH*CH*sizeof(float);       // 21.2 MB
  const size_t offX  = 0;
  const size_t offWT = offX + X_BYTES;
  const size_t offC  = offWT + WT_BYTES;
  const size_t offE  = offC + C_BYTES;
  const size_t offChunk = offE + 4096;                          // ~103.8 MB
  const size_t perF = (size_t)CH*CH*sizeof(float2);             // 512 KB

  float2* X  = (float2*)(ws + offX);
  float*  wT = (float*)(ws + offWT);
  float*  C2 = (float*)(ws + offC);
  float*  eb = (float*)(ws + offE);
  float2* U  = (float2*)(ws + offChunk);   // forward intermediate (dead before chunks)
  float2* Mb = (float2*)(ws + offChunk);   // per-chunk M buffers
  float2* Y  = (float2*)(ws + offChunk);   // inverse intermediate (after chunks)

  size_t avail = ws_size > offChunk ? ws_size - offChunk : 0;
  int F = (int)(avail / perF);
  if (F < 1) F = 1;
  if (F > NFREQ) F = NFREQ;
  int nch = (NFREQ + F - 1) / F;
  F = (NFREQ + nch - 1) / nch;   // equalize chunk sizes

  kF1<<<dim3(CH, 8), 256, 0, stream>>>(x, U);
  kF2<<<dim3(NFH, 32), 512, 0, stream>>>(U, X);
  kT0<<<(9*CH*CIN + 255)/256, 256, 0, stream>>>(w, wT);
  kC<<<dim3(81, 16), 256, 0, stream>>>(wT, C2);

  for (int cf0 = 0; cf0 < NFREQ; cf0 += F){
    int cF = (NFREQ - cf0 < F) ? (NFREQ - cf0) : F;
    kM<<<dim3(CH, 8, (cF + 63) >> 6), 64, 0, stream>>>(C2, Mb, cf0, cF);
    kEps<<<cF, 256, 0, stream>>>(Mb, eb, cf0);
    kChol<<<cF, 256, 0, stream>>>(Mb);
    kSolve<<<cF, 256, 0, stream>>>(Mb, X, eb, cf0);
  }

  kI1<<<dim3(NFH, 32), 512, 0, stream>>>(X, Y);
  kI2<<<dim3(CH, 8), 256, 0, stream>>>(Y, bias, out);
}

// Round 2
// 5996.515 us; speedup vs baseline: 1.2650x; 1.2650x over previous
//
#include <hip/hip_runtime.h>
#include <math.h>

#define NN    34
#define NFH   18
#define NFREQ 612
#define CH    256
#define CIN   255
#define NB    64
#define HW    32
#define PI2   6.2831853071795864769f

// ---------------- forward FFT stage 1: along w (real -> 18 complex) --------
// x: (B=64, C=256, 32, 32)   U[a][kx][c][b]
__global__ __launch_bounds__(256) void kF1(const float* __restrict__ x, float2* __restrict__ U){
  __shared__ float tc[NFH][HW], ts[NFH][HW];
  int tid = threadIdx.x;
  for (int i = tid; i < NFH*HW; i += 256){
    int kx = i >> 5, w = i & 31;
    float s, c; sincosf(-PI2*(float)(kx*(w+1))/34.f, &s, &c);
    tc[kx][w] = c; ts[kx][w] = s;
  }
  __syncthreads();
  int c = blockIdx.x;
  int a = (blockIdx.y << 2) + (tid >> 6);
  int b = tid & 63;
  const float4* xr = (const float4*)(x + (((size_t)b*CH + c)*HW + a)*HW);
  float xv[HW];
#pragma unroll
  for (int t = 0; t < 8; t++){
    float4 v = xr[t];
    xv[4*t] = v.x; xv[4*t+1] = v.y; xv[4*t+2] = v.z; xv[4*t+3] = v.w;
  }
#pragma unroll 1
  for (int kx = 0; kx < NFH; kx++){
    float re = 0.f, im = 0.f;
#pragma unroll
    for (int w = 0; w < HW; w++){ re += xv[w]*tc[kx][w]; im += xv[w]*ts[kx][w]; }
    U[(((size_t)a*NFH + kx)*CH + c)*NB + b] = make_float2(re, im);
  }
}

// ---------------- forward FFT stage 2: along a (32 -> 34 complex), scale 1/34
// X[f=ky*18+kx][c][b]
__global__ __launch_bounds__(512) void kF2(const float2* __restrict__ U, float2* __restrict__ X){
  __shared__ float pc[NN][HW], ps[NN][HW];
  int tid = threadIdx.x;
  for (int i = tid; i < NN*HW; i += 512){
    int ky = i >> 5, a = i & 31;
    float s, c; sincosf(-PI2*(float)(ky*(a+1))/34.f, &s, &c);
    pc[ky][a] = c*(1.f/34.f); ps[ky][a] = s*(1.f/34.f);
  }
  __syncthreads();
  int kx = blockIdx.x;
  int c  = (blockIdx.y << 3) + (tid >> 6);
  int b  = tid & 63;
  float2 u[HW];
#pragma unroll
  for (int a = 0; a < HW; a++) u[a] = U[(((size_t)a*NFH + kx)*CH + c)*NB + b];
#pragma unroll 1
  for (int ky = 0; ky < NN; ky++){
    float re = 0.f, im = 0.f;
#pragma unroll
    for (int a = 0; a < HW; a++){
      float cc = pc[ky][a], ss = ps[ky][a];
      re += u[a].x*cc - u[a].y*ss;
      im += u[a].x*ss + u[a].y*cc;
    }
    X[(((size_t)ky*NFH + kx)*CH + c)*NB + b] = make_float2(re, im);
  }
}

// ---------------- transpose weight: wT[k][o*255+i] = w[o][i][k] ------------
__global__ __launch_bounds__(256) void kT0(const float* __restrict__ w, float* __restrict__ wT){
  int idx = blockIdx.x*256 + threadIdx.x;
  if (idx >= 9*CH*CIN) return;
  int k = idx / (CH*CIN);
  int r = idx - k*(CH*CIN);
  wT[idx] = w[(size_t)r*9 + k];
}

// ---------------- C2[kk=k1*9+k2][o][p] = sum_i w[o,i,k1]*w[p,i,k2] ---------
__global__ __launch_bounds__(256) void kC(const float* __restrict__ wT, float* __restrict__ C2){
  int kk = blockIdx.x;
  int k1 = kk / 9, k2 = kk - k1*9;
  int to = (blockIdx.y >> 2) << 6, tp = (blockIdx.y & 3) << 6;
  __shared__ float As[64][33], Bs[64][33];
  int tid = threadIdx.x;
  int ty = tid >> 4, tx = tid & 15;
  float acc[4][4] = {};
  const float* Ab = wT + (size_t)k1*CH*CIN;
  const float* Bb = wT + (size_t)k2*CH*CIN;
  for (int i0 = 0; i0 < CIN; i0 += 32){
    for (int idx = tid; idx < 64*32; idx += 256){
      int r = idx >> 5, j = idx & 31;
      int i = i0 + j;
      As[r][j] = (i < CIN) ? Ab[(size_t)(to + r)*CIN + i] : 0.f;
      Bs[r][j] = (i < CIN) ? Bb[(size_t)(tp + r)*CIN + i] : 0.f;
    }
    __syncthreads();
#pragma unroll
    for (int j = 0; j < 32; j++){
      float av[4], bv[4];
#pragma unroll
      for (int d = 0; d < 4; d++){ av[d] = As[ty*4+d][j]; bv[d] = Bs[tx*4+d][j]; }
#pragma unroll
      for (int da = 0; da < 4; da++)
#pragma unroll
        for (int db = 0; db < 4; db++) acc[da][db] += av[da]*bv[db];
    }
    __syncthreads();
  }
  float* Cb = C2 + (size_t)kk*CH*CH;
#pragma unroll
  for (int da = 0; da < 4; da++)
#pragma unroll
    for (int db = 0; db < 4; db++)
      Cb[(size_t)(to + ty*4 + da)*CH + tp + tx*4 + db] = acc[da][db];
}

// ---------------- M[f][o][p] = sum_kk coef(f,kk) * C2[kk][o][p] ------------
__global__ __launch_bounds__(64) void kM(const float* __restrict__ C2, float2* __restrict__ M, int cf0, int cF){
  int o  = blockIdx.x;
  int p0 = blockIdx.y << 5;
  int fl = (blockIdx.z << 6) + threadIdx.x;
  bool act = fl < cF;
  int f = act ? (cf0 + fl) : 0;
  int ky = f / NFH, kx = f - ky*NFH;
  float Pc[5], Ps[5], Qc[5], Qs[5];
#pragma unroll
  for (int d = 0; d < 5; d++){
    float s, c;
    sincosf(-PI2*(float)(ky*(d-2))/34.f, &s, &c);
    Pc[d] = c*(1.f/1156.f); Ps[d] = s*(1.f/1156.f);
    sincosf(-PI2*(float)(kx*(d-2))/34.f, &s, &c);
    Qc[d] = c; Qs[d] = s;
  }
  float ax[32] = {}, ay[32] = {};
  const float* Cb = C2 + (size_t)o*CH + p0;
#pragma unroll 1
  for (int k1 = 0; k1 < 9; k1++){
#pragma unroll 1
    for (int k2 = 0; k2 < 9; k2++){
      int da = k1/3 - k2/3 + 2, db = k1%3 - k2%3 + 2;
      float cr = Pc[da]*Qc[db] - Ps[da]*Qs[db];
      float ci = Pc[da]*Qs[db] + Ps[da]*Qc[db];
      const float* crow = Cb + (size_t)(k1*9 + k2)*CH*CH;
#pragma unroll
      for (int j = 0; j < 32; j++){
        float cv = crow[j];
        ax[j] += cv*cr; ay[j] += cv*ci;
      }
    }
  }
  if (act){
    float2* Mr = M + ((size_t)fl*CH + o)*CH + p0;
#pragma unroll
    for (int j = 0; j < 32; j++) Mr[j] = make_float2(ax[j], ay[j]);
  }
}

// ---------------- eps = 1e-5 * trace(M)/255 ; M += eps*I -------------------
__global__ __launch_bounds__(256) void kEps(float2* __restrict__ M, float* __restrict__ eb, int cf0){
  int fi = blockIdx.x;
  float2* Mf = M + (size_t)fi*CH*CH;
  int o = threadIdx.x;
  __shared__ float red[256];
  float d = Mf[(size_t)o*CH + o].x;
  red[o] = d;
  __syncthreads();
  for (int s = 128; s > 0; s >>= 1){ if (o < s) red[o] += red[o+s]; __syncthreads(); }
  float eps = red[0] * (1e-5f/255.f);
  Mf[(size_t)o*CH + o].x = d + eps;
  if (o == 0) eb[cf0 + fi] = eps;
}

// ---------------- blocked in-place Cholesky (lower), also store conj-T upper
__global__ __launch_bounds__(256) void kChol(float2* __restrict__ Mg){
  int fi = blockIdx.x;
  float2* A = Mg + (size_t)fi*CH*CH;
  __shared__ float2 P[256][33];
  int tid = threadIdx.x;
  for (int pb = 0; pb < 8; pb++){
    int c0 = pb << 5, h = CH - c0;
    for (int idx = tid; idx < h*32; idx += 256){
      int r = idx >> 5, j = idx & 31;
      P[r][j] = A[(size_t)(c0+r)*CH + c0 + j];
    }
    __syncthreads();
    for (int k = 0; k < 32; k++){
      float d = sqrtf(fmaxf(P[k][k].x, 1e-20f));
      float inv = 1.f/d;
      __syncthreads();
      for (int i = k+1+tid; i < h; i += 256){ P[i][k].x *= inv; P[i][k].y *= inv; }
      if (tid == 0) P[k][k] = make_float2(d, 0.f);
      __syncthreads();
      for (int j = k+1; j < 32; j++){
        float2 lj = P[j][k];
        for (int i = j+tid; i < h; i += 256){
          float2 li = P[i][k];
          P[i][j].x -= li.x*lj.x + li.y*lj.y;
          P[i][j].y -= li.y*lj.x - li.x*lj.y;
        }
      }
      __syncthreads();
    }
    for (int idx = tid; idx < h*32; idx += 256){
      int r = idx >> 5, j = idx & 31;
      A[(size_t)(c0+r)*CH + c0 + j] = P[r][j];
    }
    for (int idx = tid; idx < 32*h; idx += 256){
      int j = idx / h, r = idx - j*h;
      if (r > j){
        float2 v = P[r][j];
        A[(size_t)(c0+j)*CH + c0 + r] = make_float2(v.x, -v.y);
      }
    }
    __syncthreads();
    int ty = tid >> 3, tx = tid & 7;
    for (int jb = pb+1; jb < 8; jb++){
      int jc0 = jb << 5;
      for (int i0 = jc0; i0 < CH; i0 += 128){
        if (i0 + ty*4 < CH){
          int rb = i0 - c0 + ty*4;
          int cb = jc0 - c0 + tx*4;
          float2 acc[4][4] = {};
#pragma unroll 4
          for (int k = 0; k < 32; k++){
            float2 av[4], bv[4];
#pragma unroll
            for (int d = 0; d < 4; d++){ av[d] = P[rb+d][k]; bv[d] = P[cb+d][k]; }
#pragma unroll
            for (int da = 0; da < 4; da++)
#pragma unroll
              for (int db = 0; db < 4; db++){
                acc[da][db].x += av[da].x*bv[db].x + av[da].y*bv[db].y;
                acc[da][db].y += av[da].y*bv[db].x - av[da].x*bv[db].y;
              }
          }
#pragma unroll
          for (int da = 0; da < 4; da++){
            int ii = i0 + ty*4 + da;
#pragma unroll
            for (int db = 0; db < 4; db++){
              int jj = jc0 + tx*4 + db;
              if (ii >= jj){
                float2* ap = A + (size_t)ii*CH + jj;
                float2 v = *ap;
                ap->x = v.x - acc[da][db].x;
                ap->y = v.y - acc[da][db].y;
              }
            }
          }
        }
      }
    }
    __syncthreads();
  }
}

// ================= blocked register-resident TRSM solve ====================
// One block = one freq. Wave w owns rows [64w,64w+64) x all 64 cols (lane=col),
// S held in 64 complex registers/thread. 16 phases: serial 32x32 diag solve in
// LDS by one wave, then rank-32 register updates (Lt reads are LDS broadcasts).
template<int LO, bool FWD>
__device__ __forceinline__ void solvePhase(int jb, const float2* __restrict__ A,
    float2 (&s)[64], float2 (&Lt)[4][2][32][32], float2 (&S32)[32][64],
    int wv, int c){
  // A: stage this phase's tiles (per-wave private slots, no barrier needed)
#pragma unroll
  for (int it2 = 0; it2 < 2; it2++){
    int ib = 2*wv + it2;
    bool need = FWD ? (ib >= jb) : (ib <= jb);
    if (need){
      const float2* src = A + (size_t)ib*32*CH + jb*32;
#pragma unroll
      for (int t = 0; t < 8; t++){
        int idx = t*64 + c;
        int row = idx >> 4, cp = idx & 15;
        float4 v = *(const float4*)(src + (size_t)row*CH + cp*2);
        *(float4*)(&Lt[wv][it2][row][cp*2]) = v;
      }
    }
  }
  // B: diagonal solve (one wave, in LDS; lane = col)
  if (wv == (jb >> 1)){
    int sl = jb & 1;
#pragma unroll
    for (int i = 0; i < 32; i++) S32[i][c] = s[LO + i];
    if (FWD){
#pragma unroll 1
      for (int k = 0; k < 32; k++){
        float dinv = __builtin_amdgcn_rcpf(Lt[wv][sl][k][k].x);
        float2 v = S32[k][c];
        v.x *= dinv; v.y *= dinv;
        S32[k][c] = v;
#pragma unroll 1
        for (int i = k+1; i < 32; i++){
          float2 l = Lt[wv][sl][i][k];
          float2 t2 = S32[i][c];
          t2.x -= l.x*v.x - l.y*v.y;
          t2.y -= l.x*v.y + l.y*v.x;
          S32[i][c] = t2;
        }
      }
    } else {
#pragma unroll 1
      for (int k = 31; k >= 0; k--){
        float dinv = __builtin_amdgcn_rcpf(Lt[wv][sl][k][k].x);
        float2 v = S32[k][c];
        v.x *= dinv; v.y *= dinv;
        S32[k][c] = v;
#pragma unroll 1
        for (int i = 0; i < k; i++){
          float2 l = Lt[wv][sl][i][k];
          float2 t2 = S32[i][c];
          t2.x -= l.x*v.x - l.y*v.y;
          t2.y -= l.x*v.y + l.y*v.x;
          S32[i][c] = t2;
        }
      }
    }
  }
  __syncthreads();
  // D: rank-32 updates into registers (Lt[i][k] wave-uniform -> broadcast)
#pragma unroll
  for (int it2 = 0; it2 < 2; it2++){
    int ib = 2*wv + it2;
    bool upd = FWD ? (ib > jb) : (ib < jb);
    if (upd){
      const int off = it2*32;
#pragma unroll 2
      for (int k = 0; k < 32; k++){
        float2 b = S32[k][c];
#pragma unroll
        for (int i = 0; i < 32; i++){
          float2 l = Lt[wv][it2][i][k];
          s[off+i].x -= l.x*b.x - l.y*b.y;
          s[off+i].y -= l.x*b.y + l.y*b.x;
        }
      }
    }
  }
  if (wv == (jb >> 1)){
#pragma unroll
    for (int i = 0; i < 32; i++) s[LO + i] = S32[i][c];
  }
  __syncthreads();
}

__global__ __launch_bounds__(256, 2) void kSolve(const float2* __restrict__ Lg, float2* __restrict__ X,
                                                 const float* __restrict__ eb, int cf0){
  __shared__ __align__(16) float2 Lt[4][2][32][32];   // 64 KiB
  __shared__ float2 S32[32][64];                       // 16 KiB -> 80 KiB total
  int fi = blockIdx.x;
  int f = cf0 + fi;
  const float2* A = Lg + (size_t)fi*CH*CH;
  float2* Xf = X + (size_t)f*CH*NB;
  int tid = threadIdx.x, wv = tid >> 6, c = tid & 63;
  float2 s[64];
#pragma unroll
  for (int i = 0; i < 64; i++) s[i] = Xf[(size_t)(wv*64 + i)*NB + c];
  // forward: L y = x
#pragma unroll 1
  for (int jp = 0; jp < 4; jp++){
    solvePhase<0,  true>(2*jp,     A, s, Lt, S32, wv, c);
    solvePhase<32, true>(2*jp + 1, A, s, Lt, S32, wv, c);
  }
  // backward: L^H z = y  (upper storage holds conj(L)^T)
#pragma unroll 1
  for (int jp = 3; jp >= 0; jp--){
    solvePhase<32, false>(2*jp + 1, A, s, Lt, S32, wv, c);
    solvePhase<0,  false>(2*jp,     A, s, Lt, S32, wv, c);
  }
  float te = 2.f * eb[f];
#pragma unroll
  for (int i = 0; i < 64; i++){
    float2 xv = Xf[(size_t)(wv*64 + i)*NB + c];
    float2 sv = s[i];
    Xf[(size_t)(wv*64 + i)*NB + c] = make_float2(te*sv.x - xv.x, te*sv.y - xv.y);
  }
}

// ---------------- inverse FFT stage 1: along ky (34 -> rows a=1..32) -------
__global__ __launch_bounds__(512) void kI1(const float2* __restrict__ X, float2* __restrict__ Y){
  __shared__ float pc[HW][NN], ps[HW][NN];
  int tid = threadIdx.x;
  for (int i = tid; i < HW*NN; i += 512){
    int a = i / NN, ky = i - a*NN;
    float s, c; sincosf(PI2*(float)(ky*(a+1))/34.f, &s, &c);
    pc[a][ky] = c; ps[a][ky] = s;
  }
  __syncthreads();
  int kx = blockIdx.x;
  int cc = (blockIdx.y << 3) + (tid >> 6);
  int b = tid & 63;
  float2 z[NN];
#pragma unroll
  for (int ky = 0; ky < NN; ky++) z[ky] = X[(((size_t)ky*NFH + kx)*CH + cc)*NB + b];
#pragma unroll 1
  for (int a = 0; a < HW; a++){
    float re = 0.f, im = 0.f;
#pragma unroll
    for (int ky = 0; ky < NN; ky++){
      float co = pc[a][ky], si = ps[a][ky];
      re += z[ky].x*co - z[ky].y*si;
      im += z[ky].x*si + z[ky].y*co;
    }
    Y[(((size_t)a*NFH + kx)*CH + cc)*NB + b] = make_float2(re, im);
  }
}

// ---------------- inverse FFT stage 2: along kx (18 -> real w=1..32) + bias
__global__ __launch_bounds__(256) void kI2(const float2* __restrict__ Y, const float* __restrict__ bias,
                                           float* __restrict__ out){
  __shared__ float tc[NFH][HW], tsn[NFH][HW];
  int tid = threadIdx.x;
  for (int i = tid; i < NFH*HW; i += 256){
    int kx = i >> 5, w = i & 31;
    float wt = (kx == 0 || kx == 17) ? (1.f/34.f) : (2.f/34.f);
    float s, c; sincosf(PI2*(float)(kx*(w+1))/34.f, &s, &c);
    tc[kx][w] = wt*c; tsn[kx][w] = wt*s;
  }
  __syncthreads();
  int cc = blockIdx.x;
  int a = (blockIdx.y << 2) + (tid >> 6);
  int b = tid & 63;
  float2 yv[NFH];
#pragma unroll
  for (int kx = 0; kx < NFH; kx++) yv[kx] = Y[(((size_t)a*NFH + kx)*CH + cc)*NB + b];
  float bi = bias[cc];
  float ov[HW];
#pragma unroll
  for (int w = 0; w < HW; w++){
    float acc = bi;
#pragma unroll
    for (int kx = 0; kx < NFH; kx++)
      acc += yv[kx].x*tc[kx][w] - yv[kx].y*tsn[kx][w];
    ov[w] = acc;
  }
  float4* op = (float4*)(out + (((size_t)b*CH + cc)*HW + a)*HW);
#pragma unroll
  for (int t = 0; t < 8; t++) op[t] = make_float4(ov[4*t], ov[4*t+1], ov[4*t+2], ov[4*t+3]);
}

extern "C" void kernel_launch(void* const* d_in, const int* in_sizes, int n_in,
                              void* d_out, int out_size, void* d_ws, size_t ws_size,
                              hipStream_t stream){
  (void)in_sizes; (void)n_in; (void)out_size;
  const float* x    = (const float*)d_in[0];
  const float* w    = (const float*)d_in[1];
  const float* bias = (const float*)d_in[2];
  float* out = (float*)d_out;
  char* ws = (char*)d_ws;

  const size_t X_BYTES  = (size_t)NFREQ*CH*NB*sizeof(float2);   // 80.2 MB
  const size_t WT_BYTES = (size_t)9*CH*CIN*sizeof(float);       // 2.35 MB
  const size_t C_BYTES  = (size_t)81*CH*CH*sizeof(float);       // 21.2 MB
  const size_t offX  = 0;
  const size_t offWT = offX + X_BYTES;
  const size_t offC  = offWT + WT_BYTES;
  const size_t offE  = offC + C_BYTES;
  const size_t offChunk = offE + 4096;                          // ~103.8 MB
  const size_t perF = (size_t)CH*CH*sizeof(float2);             // 512 KB

  float2* X  = (float2*)(ws + offX);
  float*  wT = (float*)(ws + offWT);
  float*  C2 = (float*)(ws + offC);
  float*  eb = (float*)(ws + offE);
  float2* U  = (float2*)(ws + offChunk);
  float2* Mb = (float2*)(ws + offChunk);
  float2* Y  = (float2*)(ws + offChunk);

  size_t avail = ws_size > offChunk ? ws_size - offChunk : 0;
  int F = (int)(avail / perF);
  if (F < 1) F = 1;
  if (F > NFREQ) F = NFREQ;
  int nch = (NFREQ + F - 1) / F;
  F = (NFREQ + nch - 1) / nch;

  kF1<<<dim3(CH, 8), 256, 0, stream>>>(x, U);
  kF2<<<dim3(NFH, 32), 512, 0, stream>>>(U, X);
  kT0<<<(9*CH*CIN + 255)/256, 256, 0, stream>>>(w, wT);
  kC<<<dim3(81, 16), 256, 0, stream>>>(wT, C2);

  for (int cf0 = 0; cf0 < NFREQ; cf0 += F){
    int cF = (NFREQ - cf0 < F) ? (NFREQ - cf0) : F;
    kM<<<dim3(CH, 8, (cF + 63) >> 6), 64, 0, stream>>>(C2, Mb, cf0, cF);
    kEps<<<cF, 256, 0, stream>>>(Mb, eb, cf0);
    kChol<<<cF, 256, 0, stream>>>(Mb);
    kSolve<<<cF, 256, 0, stream>>>(Mb, X, eb, cf0);
  }

  kI1<<<dim3(NFH, 32), 512, 0, stream>>>(X, Y);
  kI2<<<dim3(CH, 8), 256, 0, stream>>>(Y, bias, out);
}

// Round 3
// 5983.412 us; speedup vs baseline: 1.2678x; 1.0022x over previous
//
#include <hip/hip_runtime.h>
#include <math.h>

#define NN    34
#define NFH   18
#define NFREQ 612
#define CH    256
#define CIN   255
#define NB    64
#define HW    32
#define PI2   6.2831853071795864769f
#define TSTRIDE 36864   // float2 per freq: 36 packed lower tiles * 1024

__device__ __forceinline__ int tIdx(int I, int J){ return ((I*(I+1))>>1) + J; }

// ---------------- forward FFT stage 1: along w (real -> 18 complex) --------
__global__ __launch_bounds__(256) void kF1(const float* __restrict__ x, float2* __restrict__ U){
  __shared__ float tc[NFH][HW], ts[NFH][HW];
  int tid = threadIdx.x;
  for (int i = tid; i < NFH*HW; i += 256){
    int kx = i >> 5, w = i & 31;
    float s, c; sincosf(-PI2*(float)(kx*(w+1))/34.f, &s, &c);
    tc[kx][w] = c; ts[kx][w] = s;
  }
  __syncthreads();
  int c = blockIdx.x;
  int a = (blockIdx.y << 2) + (tid >> 6);
  int b = tid & 63;
  const float4* xr = (const float4*)(x + (((size_t)b*CH + c)*HW + a)*HW);
  float xv[HW];
#pragma unroll
  for (int t = 0; t < 8; t++){
    float4 v = xr[t];
    xv[4*t] = v.x; xv[4*t+1] = v.y; xv[4*t+2] = v.z; xv[4*t+3] = v.w;
  }
#pragma unroll 1
  for (int kx = 0; kx < NFH; kx++){
    float re = 0.f, im = 0.f;
#pragma unroll
    for (int w = 0; w < HW; w++){ re += xv[w]*tc[kx][w]; im += xv[w]*ts[kx][w]; }
    U[(((size_t)a*NFH + kx)*CH + c)*NB + b] = make_float2(re, im);
  }
}

// ---------------- forward FFT stage 2: along a (32 -> 34 complex), scale 1/34
__global__ __launch_bounds__(512) void kF2(const float2* __restrict__ U, float2* __restrict__ X){
  __shared__ float pc[NN][HW], ps[NN][HW];
  int tid = threadIdx.x;
  for (int i = tid; i < NN*HW; i += 512){
    int ky = i >> 5, a = i & 31;
    float s, c; sincosf(-PI2*(float)(ky*(a+1))/34.f, &s, &c);
    pc[ky][a] = c*(1.f/34.f); ps[ky][a] = s*(1.f/34.f);
  }
  __syncthreads();
  int kx = blockIdx.x;
  int c  = (blockIdx.y << 3) + (tid >> 6);
  int b  = tid & 63;
  float2 u[HW];
#pragma unroll
  for (int a = 0; a < HW; a++) u[a] = U[(((size_t)a*NFH + kx)*CH + c)*NB + b];
#pragma unroll 1
  for (int ky = 0; ky < NN; ky++){
    float re = 0.f, im = 0.f;
#pragma unroll
    for (int a = 0; a < HW; a++){
      float cc = pc[ky][a], ss = ps[ky][a];
      re += u[a].x*cc - u[a].y*ss;
      im += u[a].x*ss + u[a].y*cc;
    }
    X[(((size_t)ky*NFH + kx)*CH + c)*NB + b] = make_float2(re, im);
  }
}

// ---------------- transpose weight: wT[k][o*255+i] = w[o][i][k] ------------
__global__ __launch_bounds__(256) void kT0(const float* __restrict__ w, float* __restrict__ wT){
  int idx = blockIdx.x*256 + threadIdx.x;
  if (idx >= 9*CH*CIN) return;
  int k = idx / (CH*CIN);
  int r = idx - k*(CH*CIN);
  wT[idx] = w[(size_t)r*9 + k];
}

// ---------------- C2[kk=k1*9+k2][o][p] = sum_i w[o,i,k1]*w[p,i,k2] ---------
__global__ __launch_bounds__(256) void kC(const float* __restrict__ wT, float* __restrict__ C2){
  int kk = blockIdx.x;
  int k1 = kk / 9, k2 = kk - k1*9;
  int to = (blockIdx.y >> 2) << 6, tp = (blockIdx.y & 3) << 6;
  __shared__ float As[64][33], Bs[64][33];
  int tid = threadIdx.x;
  int ty = tid >> 4, tx = tid & 15;
  float acc[4][4] = {};
  const float* Ab = wT + (size_t)k1*CH*CIN;
  const float* Bb = wT + (size_t)k2*CH*CIN;
  for (int i0 = 0; i0 < CIN; i0 += 32){
    for (int idx = tid; idx < 64*32; idx += 256){
      int r = idx >> 5, j = idx & 31;
      int i = i0 + j;
      As[r][j] = (i < CIN) ? Ab[(size_t)(to + r)*CIN + i] : 0.f;
      Bs[r][j] = (i < CIN) ? Bb[(size_t)(tp + r)*CIN + i] : 0.f;
    }
    __syncthreads();
#pragma unroll
    for (int j = 0; j < 32; j++){
      float av[4], bv[4];
#pragma unroll
      for (int d = 0; d < 4; d++){ av[d] = As[ty*4+d][j]; bv[d] = Bs[tx*4+d][j]; }
#pragma unroll
      for (int da = 0; da < 4; da++)
#pragma unroll
        for (int db = 0; db < 4; db++) acc[da][db] += av[da]*bv[db];
    }
    __syncthreads();
  }
  float* Cb = C2 + (size_t)kk*CH*CH;
#pragma unroll
  for (int da = 0; da < 4; da++)
#pragma unroll
    for (int db = 0; db < 4; db++)
      Cb[(size_t)(to + ty*4 + da)*CH + tp + tx*4 + db] = acc[da][db];
}

// ---------------- M: packed lower tiles only. block=(tile t, row r, fgrp) ---
__global__ __launch_bounds__(64) void kM(const float* __restrict__ C2, float2* __restrict__ M, int cf0, int cF){
  int t = blockIdx.x;
  int I = 0;
  while ((((I+1)*(I+2))>>1) <= t) I++;
  int J = t - ((I*(I+1))>>1);
  int r = blockIdx.y;
  int o = I*32 + r, p0 = J*32;
  int fl = (blockIdx.z << 6) + threadIdx.x;
  bool act = fl < cF;
  int f = act ? (cf0 + fl) : 0;
  int ky = f / NFH, kx = f - ky*NFH;
  float Pc[5], Ps[5], Qc[5], Qs[5];
#pragma unroll
  for (int d = 0; d < 5; d++){
    float s, c;
    sincosf(-PI2*(float)(ky*(d-2))/34.f, &s, &c);
    Pc[d] = c*(1.f/1156.f); Ps[d] = s*(1.f/1156.f);
    sincosf(-PI2*(float)(kx*(d-2))/34.f, &s, &c);
    Qc[d] = c; Qs[d] = s;
  }
  float ax[32] = {}, ay[32] = {};
  const float* Cb = C2 + (size_t)o*CH + p0;
#pragma unroll 1
  for (int k1 = 0; k1 < 9; k1++){
#pragma unroll 1
    for (int k2 = 0; k2 < 9; k2++){
      int da = k1/3 - k2/3 + 2, db = k1%3 - k2%3 + 2;
      float cr = Pc[da]*Qc[db] - Ps[da]*Qs[db];
      float ci = Pc[da]*Qs[db] + Ps[da]*Qc[db];
      const float* crow = Cb + (size_t)(k1*9 + k2)*CH*CH;
#pragma unroll
      for (int j = 0; j < 32; j++){
        float cv = crow[j];
        ax[j] += cv*cr; ay[j] += cv*ci;
      }
    }
  }
  if (act){
    float2* Mr = M + (size_t)fl*TSTRIDE + ((size_t)t << 10) + (r << 5);
#pragma unroll
    for (int j = 0; j < 32; j++) Mr[j] = make_float2(ax[j], ay[j]);
  }
}

// ---------------- eps = 1e-5 * trace(M)/255 ; diag += eps (packed) ---------
__global__ __launch_bounds__(256) void kEps(float2* __restrict__ M, float* __restrict__ eb, int cf0){
  int fi = blockIdx.x;
  int o = threadIdx.x;
  int I = o >> 5, r = o & 31;
  float2* Mf = M + (size_t)fi*TSTRIDE + ((size_t)tIdx(I,I) << 10) + r*32 + r;
  __shared__ float red[256];
  float d = Mf->x;
  red[o] = d;
  __syncthreads();
  for (int s = 128; s > 0; s >>= 1){ if (o < s) red[o] += red[o+s]; __syncthreads(); }
  float eps = red[0] * (1e-5f/255.f);
  Mf->x = d + eps;
  if (o == 0) eb[cf0 + fi] = eps;
}

// ============ left-looking register-resident Cholesky (packed tiles) =======
// One block = one freq, 256 threads. Thread (ty=tid>>3, jg=tid&7) owns panel
// rows 32s+ty (s=0..nblk-1), cols 4jg..4jg+3, in registers pA[8][4].
__global__ __launch_bounds__(256) void kFact(float2* __restrict__ Mg){
  __shared__ float2 Ah[2][32][33];
  __shared__ float2 Bs2[32][33];
  __shared__ float2 Dg[32][33];
  float2* Tf = Mg + (size_t)blockIdx.x * TSTRIDE;
  const int tid = threadIdx.x;
  const int ty = tid >> 3, jg = tid & 7;
  const int tyw8 = ((tid & 63) >> 3) << 3;
  float2 pA[8][4];

#define LD4(dst, I_, J_) { \
    const float2* sp_ = Tf + ((size_t)tIdx((I_),(J_)) << 10) + ty*32 + jg*4; \
    float4 v0_ = *(const float4*)(sp_); \
    float4 v1_ = *(const float4*)(sp_ + 2); \
    dst[0] = make_float2(v0_.x, v0_.y); dst[1] = make_float2(v0_.z, v0_.w); \
    dst[2] = make_float2(v1_.x, v1_.y); dst[3] = make_float2(v1_.z, v1_.w); }

#define STG(arr, I_, J_) { \
    float2 t_[4]; LD4(t_, I_, J_); \
    arr[ty][jg*4+0] = t_[0]; arr[ty][jg*4+1] = t_[1]; \
    arr[ty][jg*4+2] = t_[2]; arr[ty][jg*4+3] = t_[3]; }

#define UPD(s_, AH) { \
    _Pragma("unroll 8") \
    for (int k = 0; k < 32; k++){ \
      float2 a_ = AH[ty][k]; \
      _Pragma("unroll") \
      for (int d = 0; d < 4; d++){ \
        float2 b_ = Bs2[4*jg+d][k]; \
        pA[s_][d].x -= a_.x*b_.x + a_.y*b_.y; \
        pA[s_][d].y -= a_.y*b_.x - a_.x*b_.y; } } }

#pragma unroll 1
  for (int pb = 0; pb < 8; pb++){
    const int nblk = 8 - pb;
    // 1. load panel into registers
#pragma unroll
    for (int s = 0; s < 8; s++) if (s < nblk) LD4(pA[s], pb+s, pb);
    // 2. history updates: pA -= L[rows][q-block] * conj(L[c0..c0+32][q-block])^T
#pragma unroll 1
    for (int q = 0; q < pb; q++){
      STG(Bs2, pb, q);
      if (nblk > 1) STG(Ah[1], pb+1, q);
      __syncthreads();
      UPD(0, Bs2);
      if (nblk == 1) __syncthreads();
#pragma unroll
      for (int s = 1; s < 8; s++) if (s < nblk){
        if (s+1 < nblk) STG(Ah[(s+1)&1], pb+s+1, q);
        UPD(s, Ah[s&1]);
        __syncthreads();
      }
    }
    // 3. diag 32x32 Cholesky, one wave, rows in registers, shfl broadcasts
    Dg[ty][jg*4+0] = pA[0][0]; Dg[ty][jg*4+1] = pA[0][1];
    Dg[ty][jg*4+2] = pA[0][2]; Dg[ty][jg*4+3] = pA[0][3];
    __syncthreads();
    if (tid < 32){
      const int i = tid;
      float2 row[32];
#pragma unroll
      for (int k = 0; k < 32; k++) row[k] = Dg[i][k];
#pragma unroll
      for (int k = 0; k < 32; k++){
        float dv = __shfl(row[k].x, k, 64);
        float dk = sqrtf(fmaxf(dv, 1e-30f));
        float dinv = __builtin_amdgcn_rcpf(dk);
        if (i > k){ row[k].x *= dinv; row[k].y *= dinv; }
        else if (i == k) row[k] = make_float2(dk, 0.f);
#pragma unroll
        for (int j = k+1; j < 32; j++){
          float ljx = __shfl(row[k].x, j, 64);
          float ljy = __shfl(row[k].y, j, 64);
          if (i >= j){
            row[j].x -= row[k].x*ljx + row[k].y*ljy;
            row[j].y -= row[k].y*ljx - row[k].x*ljy;
          }
        }
      }
      float2* drow = Tf + ((size_t)tIdx(pb,pb) << 10) + i*32;
#pragma unroll
      for (int k = 0; k < 32; k++){ Dg[i][k] = row[k]; drow[k] = row[k]; }
    }
    __syncthreads();
    if (nblk > 1){
      // 4. TRSM: rows solve x * L11^H = a via in-wave shfl (owner lane = col k)
#pragma unroll
      for (int k = 0; k < 32; k++){
        const int dk = k & 3;
        const int srcl = tyw8 + (k >> 2);
        const float dinv = __builtin_amdgcn_rcpf(Dg[k][k].x);
#pragma unroll
        for (int s = 1; s < 8; s++) if (s < nblk){
          float xx = pA[s][dk].x * dinv, xy = pA[s][dk].y * dinv;
          xx = __shfl(xx, srcl, 64);
          xy = __shfl(xy, srcl, 64);
          if (jg == (k >> 2)) pA[s][dk] = make_float2(xx, xy);
#pragma unroll
          for (int d = 0; d < 4; d++){
            if (4*jg + d > k){
              float2 l = Dg[4*jg+d][k];
              pA[s][d].x -= xx*l.x + xy*l.y;
              pA[s][d].y -= xy*l.x - xx*l.y;
            }
          }
        }
      }
      // 5. writeback L21 tiles
#pragma unroll
      for (int s = 1; s < 8; s++) if (s < nblk){
        float2* dst = Tf + ((size_t)tIdx(pb+s, pb) << 10) + ty*32 + jg*4;
        *(float4*)(dst)     = make_float4(pA[s][0].x, pA[s][0].y, pA[s][1].x, pA[s][1].y);
        *(float4*)(dst + 2) = make_float4(pA[s][2].x, pA[s][2].y, pA[s][3].x, pA[s][3].y);
      }
    }
    __threadfence();
    __syncthreads();
  }
#undef LD4
#undef STG
#undef UPD
}

// ================= blocked register-resident TRSM solve ====================
template<int LO, bool FWD>
__device__ __forceinline__ void solvePhase(int jb, const float2* __restrict__ Tf,
    float2 (&s)[64], float2 (&Lt)[4][2][32][32], float2 (&S32)[32][64],
    int wv, int c){
  // stage tiles (fwd: lower tile as-is; bwd: conj-transpose of lower tile)
#pragma unroll
  for (int it2 = 0; it2 < 2; it2++){
    int ib = 2*wv + it2;
    if (FWD ? (ib >= jb) : (ib <= jb)){
      if (FWD){
        const float2* src = Tf + ((size_t)tIdx(ib, jb) << 10);
#pragma unroll
        for (int t = 0; t < 8; t++){
          int idx = t*64 + c, row = idx >> 4, cp = idx & 15;
          float4 v = *(const float4*)(src + row*32 + cp*2);
          *(float4*)(&Lt[wv][it2][row][cp*2]) = v;
        }
      } else {
        const float2* src = Tf + ((size_t)tIdx(jb, ib) << 10);
#pragma unroll
        for (int t = 0; t < 8; t++){
          int idx = t*64 + c, row = idx >> 4, cp = idx & 15;
          float4 v = *(const float4*)(src + row*32 + cp*2);
          Lt[wv][it2][cp*2  ][row] = make_float2(v.x, -v.y);
          Lt[wv][it2][cp*2+1][row] = make_float2(v.z, -v.w);
        }
      }
    }
  }
  // diagonal solve (owning wave, in LDS; lane = col)
  if (wv == (jb >> 1)){
    int sl = jb & 1;
#pragma unroll
    for (int i = 0; i < 32; i++) S32[i][c] = s[LO + i];
    if (FWD){
#pragma unroll 1
      for (int k = 0; k < 32; k++){
        float dinv = __builtin_amdgcn_rcpf(Lt[wv][sl][k][k].x);
        float2 v = S32[k][c];
        v.x *= dinv; v.y *= dinv;
        S32[k][c] = v;
#pragma unroll 1
        for (int i = k+1; i < 32; i++){
          float2 l = Lt[wv][sl][i][k];
          float2 t2 = S32[i][c];
          t2.x -= l.x*v.x - l.y*v.y;
          t2.y -= l.x*v.y + l.y*v.x;
          S32[i][c] = t2;
        }
      }
    } else {
#pragma unroll 1
      for (int k = 31; k >= 0; k--){
        float dinv = __builtin_amdgcn_rcpf(Lt[wv][sl][k][k].x);
        float2 v = S32[k][c];
        v.x *= dinv; v.y *= dinv;
        S32[k][c] = v;
#pragma unroll 1
        for (int i = 0; i < k; i++){
          float2 l = Lt[wv][sl][i][k];
          float2 t2 = S32[i][c];
          t2.x -= l.x*v.x - l.y*v.y;
          t2.y -= l.x*v.y + l.y*v.x;
          S32[i][c] = t2;
        }
      }
    }
  }
  __syncthreads();
  // rank-32 register updates (Lt reads wave-uniform -> broadcast)
#pragma unroll
  for (int it2 = 0; it2 < 2; it2++){
    int ib = 2*wv + it2;
    bool upd = FWD ? (ib > jb) : (ib < jb);
    if (upd){
      const int off = it2*32;
#pragma unroll 2
      for (int k = 0; k < 32; k++){
        float2 b = S32[k][c];
#pragma unroll
        for (int i = 0; i < 32; i++){
          float2 l = Lt[wv][it2][i][k];
          s[off+i].x -= l.x*b.x - l.y*b.y;
          s[off+i].y -= l.x*b.y + l.y*b.x;
        }
      }
    }
  }
  if (wv == (jb >> 1)){
#pragma unroll
    for (int i = 0; i < 32; i++) s[LO + i] = S32[i][c];
  }
  __syncthreads();
}

__global__ __launch_bounds__(256, 2) void kSolve(const float2* __restrict__ Lg, float2* __restrict__ X,
                                                 const float* __restrict__ eb, int cf0){
  __shared__ __align__(16) float2 Lt[4][2][32][32];   // 64 KiB
  __shared__ float2 S32[32][64];                       // 16 KiB
  int fi = blockIdx.x;
  int f = cf0 + fi;
  const float2* Tf = Lg + (size_t)fi*TSTRIDE;
  float2* Xf = X + (size_t)f*CH*NB;
  int tid = threadIdx.x, wv = tid >> 6, c = tid & 63;
  float2 s[64];
#pragma unroll
  for (int i = 0; i < 64; i++) s[i] = Xf[(size_t)(wv*64 + i)*NB + c];
#pragma unroll 1
  for (int jp = 0; jp < 4; jp++){
    solvePhase<0,  true>(2*jp,     Tf, s, Lt, S32, wv, c);
    solvePhase<32, true>(2*jp + 1, Tf, s, Lt, S32, wv, c);
  }
#pragma unroll 1
  for (int jp = 3; jp >= 0; jp--){
    solvePhase<32, false>(2*jp + 1, Tf, s, Lt, S32, wv, c);
    solvePhase<0,  false>(2*jp,     Tf, s, Lt, S32, wv, c);
  }
  float te = 2.f * eb[f];
#pragma unroll
  for (int i = 0; i < 64; i++){
    float2 xv = Xf[(size_t)(wv*64 + i)*NB + c];
    float2 sv = s[i];
    Xf[(size_t)(wv*64 + i)*NB + c] = make_float2(te*sv.x - xv.x, te*sv.y - xv.y);
  }
}

// ---------------- inverse FFT stage 1: along ky (34 -> rows a=1..32) -------
__global__ __launch_bounds__(512) void kI1(const float2* __restrict__ X, float2* __restrict__ Y){
  __shared__ float pc[HW][NN], ps[HW][NN];
  int tid = threadIdx.x;
  for (int i = tid; i < HW*NN; i += 512){
    int a = i / NN, ky = i - a*NN;
    float s, c; sincosf(PI2*(float)(ky*(a+1))/34.f, &s, &c);
    pc[a][ky] = c; ps[a][ky] = s;
  }
  __syncthreads();
  int kx = blockIdx.x;
  int cc = (blockIdx.y << 3) + (tid >> 6);
  int b = tid & 63;
  float2 z[NN];
#pragma unroll
  for (int ky = 0; ky < NN; ky++) z[ky] = X[(((size_t)ky*NFH + kx)*CH + cc)*NB + b];
#pragma unroll 1
  for (int a = 0; a < HW; a++){
    float re = 0.f, im = 0.f;
#pragma unroll
    for (int ky = 0; ky < NN; ky++){
      float co = pc[a][ky], si = ps[a][ky];
      re += z[ky].x*co - z[ky].y*si;
      im += z[ky].x*si + z[ky].y*co;
    }
    Y[(((size_t)a*NFH + kx)*CH + cc)*NB + b] = make_float2(re, im);
  }
}

// ---------------- inverse FFT stage 2: along kx (18 -> real w=1..32) + bias
__global__ __launch_bounds__(256) void kI2(const float2* __restrict__ Y, const float* __restrict__ bias,
                                           float* __restrict__ out){
  __shared__ float tc[NFH][HW], tsn[NFH][HW];
  int tid = threadIdx.x;
  for (int i = tid; i < NFH*HW; i += 256){
    int kx = i >> 5, w = i & 31;
    float wt = (kx == 0 || kx == 17) ? (1.f/34.f) : (2.f/34.f);
    float s, c; sincosf(PI2*(float)(kx*(w+1))/34.f, &s, &c);
    tc[kx][w] = wt*c; tsn[kx][w] = wt*s;
  }
  __syncthreads();
  int cc = blockIdx.x;
  int a = (blockIdx.y << 2) + (tid >> 6);
  int b = tid & 63;
  float2 yv[NFH];
#pragma unroll
  for (int kx = 0; kx < NFH; kx++) yv[kx] = Y[(((size_t)a*NFH + kx)*CH + cc)*NB + b];
  float bi = bias[cc];
  float ov[HW];
#pragma unroll
  for (int w = 0; w < HW; w++){
    float acc = bi;
#pragma unroll
    for (int kx = 0; kx < NFH; kx++)
      acc += yv[kx].x*tc[kx][w] - yv[kx].y*tsn[kx][w];
    ov[w] = acc;
  }
  float4* op = (float4*)(out + (((size_t)b*CH + cc)*HW + a)*HW);
#pragma unroll
  for (int t = 0; t < 8; t++) op[t] = make_float4(ov[4*t], ov[4*t+1], ov[4*t+2], ov[4*t+3]);
}

extern "C" void kernel_launch(void* const* d_in, const int* in_sizes, int n_in,
                              void* d_out, int out_size, void* d_ws, size_t ws_size,
                              hipStream_t stream){
  (void)in_sizes; (void)n_in; (void)out_size;
  const float* x    = (const float*)d_in[0];
  const float* w    = (const float*)d_in[1];
  const float* bias = (const float*)d_in[2];
  float* out = (float*)d_out;
  char* ws = (char*)d_ws;

  const size_t X_BYTES  = (size_t)NFREQ*CH*NB*sizeof(float2);   // 80.2 MB
  const size_t WT_BYTES = (size_t)9*CH*CIN*sizeof(float);       // 2.35 MB
  const size_t C_BYTES  = (size_t)81*CH*CH*sizeof(float);       // 21.2 MB
  const size_t offX  = 0;
  const size_t offWT = offX + X_BYTES;
  const size_t offC  = offWT + WT_BYTES;
  const size_t offE  = offC + C_BYTES;
  const size_t offChunk = offE + 4096;
  const size_t perF = (size_t)TSTRIDE * sizeof(float2);          // 288 KB

  float2* X  = (float2*)(ws + offX);
  float*  wT = (float*)(ws + offWT);
  float*  C2 = (float*)(ws + offC);
  float*  eb = (float*)(ws + offE);
  float2* U  = (float2*)(ws + offChunk);
  float2* Mb = (float2*)(ws + offChunk);
  float2* Y  = (float2*)(ws + offChunk);

  size_t avail = ws_size > offChunk ? ws_size - offChunk : 0;
  int F = (int)(avail / perF);
  if (F < 1) F = 1;
  if (F > NFREQ) F = NFREQ;
  int nch = (NFREQ + F - 1) / F;
  F = (NFREQ + nch - 1) / nch;

  kF1<<<dim3(CH, 8), 256, 0, stream>>>(x, U);
  kF2<<<dim3(NFH, 32), 512, 0, stream>>>(U, X);
  kT0<<<(9*CH*CIN + 255)/256, 256, 0, stream>>>(w, wT);
  kC<<<dim3(81, 16), 256, 0, stream>>>(wT, C2);

  for (int cf0 = 0; cf0 < NFREQ; cf0 += F){
    int cF = (NFREQ - cf0 < F) ? (NFREQ - cf0) : F;
    kM<<<dim3(36, 32, (cF + 63) >> 6), 64, 0, stream>>>(C2, Mb, cf0, cF);
    kEps<<<cF, 256, 0, stream>>>(Mb, eb, cf0);
    kFact<<<cF, 256, 0, stream>>>(Mb);
    kSolve<<<cF, 256, 0, stream>>>(Mb, X, eb, cf0);
  }

  kI1<<<dim3(NFH, 32), 512, 0, stream>>>(X, Y);
  kI2<<<dim3(CH, 8), 256, 0, stream>>>(Y, bias, out);
}

// Round 4
// 4237.476 us; speedup vs baseline: 1.7901x; 1.4120x over previous
//
#include <hip/hip_runtime.h>
#include <math.h>

#define NN    34
#define NFH   18
#define NFREQ 612
#define CH    256
#define CIN   255
#define NB    64
#define HW    32
#define PI2   6.2831853071795864769f
#define TSTRIDE 36864   // float2 per freq: 36 packed lower tiles * 1024

__device__ __forceinline__ int tIdx(int I, int J){ return ((I*(I+1))>>1) + J; }

// ---------------- forward FFT stage 1: along w (real -> 18 complex) --------
__global__ __launch_bounds__(256) void kF1(const float* __restrict__ x, float2* __restrict__ U){
  __shared__ float tc[NFH][HW], ts[NFH][HW];
  int tid = threadIdx.x;
  for (int i = tid; i < NFH*HW; i += 256){
    int kx = i >> 5, w = i & 31;
    float s, c; sincosf(-PI2*(float)(kx*(w+1))/34.f, &s, &c);
    tc[kx][w] = c; ts[kx][w] = s;
  }
  __syncthreads();
  int c = blockIdx.x;
  int a = (blockIdx.y << 2) + (tid >> 6);
  int b = tid & 63;
  const float4* xr = (const float4*)(x + (((size_t)b*CH + c)*HW + a)*HW);
  float xv[HW];
#pragma unroll
  for (int t = 0; t < 8; t++){
    float4 v = xr[t];
    xv[4*t] = v.x; xv[4*t+1] = v.y; xv[4*t+2] = v.z; xv[4*t+3] = v.w;
  }
#pragma unroll 1
  for (int kx = 0; kx < NFH; kx++){
    float re = 0.f, im = 0.f;
#pragma unroll
    for (int w = 0; w < HW; w++){ re += xv[w]*tc[kx][w]; im += xv[w]*ts[kx][w]; }
    U[(((size_t)a*NFH + kx)*CH + c)*NB + b] = make_float2(re, im);
  }
}

// ---------------- forward FFT stage 2: along a (32 -> 34 complex), scale 1/34
__global__ __launch_bounds__(512) void kF2(const float2* __restrict__ U, float2* __restrict__ X){
  __shared__ float pc[NN][HW], ps[NN][HW];
  int tid = threadIdx.x;
  for (int i = tid; i < NN*HW; i += 512){
    int ky = i >> 5, a = i & 31;
    float s, c; sincosf(-PI2*(float)(ky*(a+1))/34.f, &s, &c);
    pc[ky][a] = c*(1.f/34.f); ps[ky][a] = s*(1.f/34.f);
  }
  __syncthreads();
  int kx = blockIdx.x;
  int c  = (blockIdx.y << 3) + (tid >> 6);
  int b  = tid & 63;
  float2 u[HW];
#pragma unroll
  for (int a = 0; a < HW; a++) u[a] = U[(((size_t)a*NFH + kx)*CH + c)*NB + b];
#pragma unroll 1
  for (int ky = 0; ky < NN; ky++){
    float re = 0.f, im = 0.f;
#pragma unroll
    for (int a = 0; a < HW; a++){
      float cc = pc[ky][a], ss = ps[ky][a];
      re += u[a].x*cc - u[a].y*ss;
      im += u[a].x*ss + u[a].y*cc;
    }
    X[(((size_t)ky*NFH + kx)*CH + c)*NB + b] = make_float2(re, im);
  }
}

// ---------------- transpose weight: wT[k][o*255+i] = w[o][i][k] ------------
__global__ __launch_bounds__(256) void kT0(const float* __restrict__ w, float* __restrict__ wT){
  int idx = blockIdx.x*256 + threadIdx.x;
  if (idx >= 9*CH*CIN) return;
  int k = idx / (CH*CIN);
  int r = idx - k*(CH*CIN);
  wT[idx] = w[(size_t)r*9 + k];
}

// ---------------- C2[kk=k1*9+k2][o][p] = sum_i w[o,i,k1]*w[p,i,k2] ---------
__global__ __launch_bounds__(256) void kC(const float* __restrict__ wT, float* __restrict__ C2){
  int kk = blockIdx.x;
  int k1 = kk / 9, k2 = kk - k1*9;
  int to = (blockIdx.y >> 2) << 6, tp = (blockIdx.y & 3) << 6;
  __shared__ float As[64][33], Bs[64][33];
  int tid = threadIdx.x;
  int ty = tid >> 4, tx = tid & 15;
  float acc[4][4] = {};
  const float* Ab = wT + (size_t)k1*CH*CIN;
  const float* Bb = wT + (size_t)k2*CH*CIN;
  for (int i0 = 0; i0 < CIN; i0 += 32){
    for (int idx = tid; idx < 64*32; idx += 256){
      int r = idx >> 5, j = idx & 31;
      int i = i0 + j;
      As[r][j] = (i < CIN) ? Ab[(size_t)(to + r)*CIN + i] : 0.f;
      Bs[r][j] = (i < CIN) ? Bb[(size_t)(tp + r)*CIN + i] : 0.f;
    }
    __syncthreads();
#pragma unroll
    for (int j = 0; j < 32; j++){
      float av[4], bv[4];
#pragma unroll
      for (int d = 0; d < 4; d++){ av[d] = As[ty*4+d][j]; bv[d] = Bs[tx*4+d][j]; }
#pragma unroll
      for (int da = 0; da < 4; da++)
#pragma unroll
        for (int db = 0; db < 4; db++) acc[da][db] += av[da]*bv[db];
    }
    __syncthreads();
  }
  float* Cb = C2 + (size_t)kk*CH*CH;
#pragma unroll
  for (int da = 0; da < 4; da++)
#pragma unroll
    for (int db = 0; db < 4; db++)
      Cb[(size_t)(to + ty*4 + da)*CH + tp + tx*4 + db] = acc[da][db];
}

// ---------------- M: packed lower tiles only. block=(tile t, row r, fgrp) ---
__global__ __launch_bounds__(64) void kM(const float* __restrict__ C2, float2* __restrict__ M, int cf0, int cF){
  int t = blockIdx.x;
  int I = 0;
  while ((((I+1)*(I+2))>>1) <= t) I++;
  int J = t - ((I*(I+1))>>1);
  int r = blockIdx.y;
  int o = I*32 + r, p0 = J*32;
  int fl = (blockIdx.z << 6) + threadIdx.x;
  bool act = fl < cF;
  int f = act ? (cf0 + fl) : 0;
  int ky = f / NFH, kx = f - ky*NFH;
  float Pc[5], Ps[5], Qc[5], Qs[5];
#pragma unroll
  for (int d = 0; d < 5; d++){
    float s, c;
    sincosf(-PI2*(float)(ky*(d-2))/34.f, &s, &c);
    Pc[d] = c*(1.f/1156.f); Ps[d] = s*(1.f/1156.f);
    sincosf(-PI2*(float)(kx*(d-2))/34.f, &s, &c);
    Qc[d] = c; Qs[d] = s;
  }
  float ax[32] = {}, ay[32] = {};
  const float* Cb = C2 + (size_t)o*CH + p0;
#pragma unroll 1
  for (int k1 = 0; k1 < 9; k1++){
#pragma unroll 1
    for (int k2 = 0; k2 < 9; k2++){
      int da = k1/3 - k2/3 + 2, db = k1%3 - k2%3 + 2;
      float cr = Pc[da]*Qc[db] - Ps[da]*Qs[db];
      float ci = Pc[da]*Qs[db] + Ps[da]*Qc[db];
      const float* crow = Cb + (size_t)(k1*9 + k2)*CH*CH;
#pragma unroll
      for (int j = 0; j < 32; j++){
        float cv = crow[j];
        ax[j] += cv*cr; ay[j] += cv*ci;
      }
    }
  }
  if (act){
    float2* Mr = M + (size_t)fl*TSTRIDE + ((size_t)t << 10) + (r << 5);
#pragma unroll
    for (int j = 0; j < 32; j++) Mr[j] = make_float2(ax[j], ay[j]);
  }
}

// ---------------- eps = 1e-5 * trace(M)/255 ; diag += eps (packed) ---------
__global__ __launch_bounds__(256) void kEps(float2* __restrict__ M, float* __restrict__ eb, int cf0){
  int fi = blockIdx.x;
  int o = threadIdx.x;
  int I = o >> 5, r = o & 31;
  float2* Mf = M + (size_t)fi*TSTRIDE + ((size_t)tIdx(I,I) << 10) + r*32 + r;
  __shared__ float red[256];
  float d = Mf->x;
  red[o] = d;
  __syncthreads();
  for (int s = 128; s > 0; s >>= 1){ if (o < s) red[o] += red[o+s]; __syncthreads(); }
  float eps = red[0] * (1e-5f/255.f);
  Mf->x = d + eps;
  if (o == 0) eb[cf0 + fi] = eps;
}

// ============ right-looking Cholesky: panel factor (one block = one freq) ===
// Factors the 32-column panel at block-column pb (height h = 256-32*pb), LDS-
// resident, all 256 threads cooperate per column; no history loop (trailing
// updates were already applied by kSyrk dispatches of earlier panels).
__global__ __launch_bounds__(256) void kPanel(float2* __restrict__ Mg, int pb){
  __shared__ float2 P[256][33];
  int fi = blockIdx.x;
  float2* Tf = Mg + (size_t)fi*TSTRIDE;
  const int h = CH - (pb << 5);
  int tid = threadIdx.x;
  for (int idx = tid; idx < h*32; idx += 256){
    int r = idx >> 5, j = idx & 31;
    P[r][j] = Tf[((size_t)tIdx(pb + (r>>5), pb) << 10) + ((r&31) << 5) + j];
  }
  __syncthreads();
  const int i = tid;
  float myd = 0.f;
  float2 lik = make_float2(0.f, 0.f);
#pragma unroll 1
  for (int k = 0; k < 32; k++){
    float pkk = P[k][k].x;              // diag not overwritten in-loop: no race
    float d = sqrtf(fmaxf(pkk, 1e-30f));
    float dinv = __builtin_amdgcn_rcpf(d);
    if (i == k) myd = d;
    bool act = (i > k) && (i < h);
    if (act){
      lik.x = P[i][k].x * dinv;
      lik.y = P[i][k].y * dinv;
      P[i][k] = lik;
    }
    __syncthreads();
    if (act){
#pragma unroll 1
      for (int j = k+1; j < 32; j++){
        if (i >= j){
          float2 ljk = P[j][k];          // wave-uniform -> LDS broadcast
          P[i][j].x -= lik.x*ljk.x + lik.y*ljk.y;   // lik * conj(ljk)
          P[i][j].y -= lik.y*ljk.x - lik.x*ljk.y;
        }
      }
    }
    __syncthreads();
  }
  if (i < 32) P[i][i] = make_float2(myd, 0.f);
  __syncthreads();
  for (int idx = tid; idx < h*32; idx += 256){
    int r = idx >> 5, j = idx & 31;
    Tf[((size_t)tIdx(pb + (r>>5), pb) << 10) + ((r&31) << 5) + j] = P[r][j];
  }
}

// ============ right-looking Cholesky: trailing SYRK/GEMM tile update ========
// block = (freq, pair p). C_IJ -= L_I,pb * (L_J,pb)^H for pb < J <= I <= 7.
__global__ __launch_bounds__(256) void kSyrk(float2* __restrict__ Mg, int pb){
  __shared__ float2 As[32][33], Bs[32][33];
  int fi = blockIdx.x;
  int p = blockIdx.y;
  int li = 0;
  while ((((li+1)*(li+2)) >> 1) <= p) li++;
  int lj = p - ((li*(li+1)) >> 1);
  int I = pb + 1 + li, J = pb + 1 + lj;
  float2* Tf = Mg + (size_t)fi*TSTRIDE;
  const float2* Asrc = Tf + ((size_t)tIdx(I, pb) << 10);
  const float2* Bsrc = Tf + ((size_t)tIdx(J, pb) << 10);
  float2* Cdst = Tf + ((size_t)tIdx(I, J) << 10);
  int tid = threadIdx.x;
  for (int idx = tid; idx < 1024; idx += 256){
    int r = idx >> 5, c = idx & 31;
    As[r][c] = Asrc[idx];
    Bs[r][c] = Bsrc[idx];
  }
  int r = tid >> 3, c0 = (tid & 7) << 2;
  float2 acc[4];
  float4 c01 = *(const float4*)(Cdst + r*32 + c0);
  float4 c23 = *(const float4*)(Cdst + r*32 + c0 + 2);
  acc[0] = make_float2(c01.x, c01.y); acc[1] = make_float2(c01.z, c01.w);
  acc[2] = make_float2(c23.x, c23.y); acc[3] = make_float2(c23.z, c23.w);
  __syncthreads();
#pragma unroll 4
  for (int k = 0; k < 32; k++){
    float2 a = As[r][k];
#pragma unroll
    for (int d = 0; d < 4; d++){
      float2 b = Bs[c0 + d][k];
      acc[d].x -= a.x*b.x + a.y*b.y;    // a * conj(b)
      acc[d].y -= a.y*b.x - a.x*b.y;
    }
  }
  *(float4*)(Cdst + r*32 + c0)     = make_float4(acc[0].x, acc[0].y, acc[1].x, acc[1].y);
  *(float4*)(Cdst + r*32 + c0 + 2) = make_float4(acc[2].x, acc[2].y, acc[3].x, acc[3].y);
}

// ================= blocked register-resident TRSM solve ====================
template<int LO, bool FWD>
__device__ __forceinline__ void solvePhase(int jb, const float2* __restrict__ Tf,
    float2 (&s)[64], float2 (&Lt)[4][2][32][32], float2 (&S32)[32][64],
    int wv, int c){
#pragma unroll
  for (int it2 = 0; it2 < 2; it2++){
    int ib = 2*wv + it2;
    if (FWD ? (ib >= jb) : (ib <= jb)){
      if (FWD){
        const float2* src = Tf + ((size_t)tIdx(ib, jb) << 10);
#pragma unroll
        for (int t = 0; t < 8; t++){
          int idx = t*64 + c, row = idx >> 4, cp = idx & 15;
          float4 v = *(const float4*)(src + row*32 + cp*2);
          *(float4*)(&Lt[wv][it2][row][cp*2]) = v;
        }
      } else {
        const float2* src = Tf + ((size_t)tIdx(jb, ib) << 10);
#pragma unroll
        for (int t = 0; t < 8; t++){
          int idx = t*64 + c, row = idx >> 4, cp = idx & 15;
          float4 v = *(const float4*)(src + row*32 + cp*2);
          Lt[wv][it2][cp*2  ][row] = make_float2(v.x, -v.y);
          Lt[wv][it2][cp*2+1][row] = make_float2(v.z, -v.w);
        }
      }
    }
  }
  if (wv == (jb >> 1)){
    int sl = jb & 1;
#pragma unroll
    for (int i = 0; i < 32; i++) S32[i][c] = s[LO + i];
    if (FWD){
#pragma unroll 1
      for (int k = 0; k < 32; k++){
        float dinv = __builtin_amdgcn_rcpf(Lt[wv][sl][k][k].x);
        float2 v = S32[k][c];
        v.x *= dinv; v.y *= dinv;
        S32[k][c] = v;
#pragma unroll 1
        for (int i = k+1; i < 32; i++){
          float2 l = Lt[wv][sl][i][k];
          float2 t2 = S32[i][c];
          t2.x -= l.x*v.x - l.y*v.y;
          t2.y -= l.x*v.y + l.y*v.x;
          S32[i][c] = t2;
        }
      }
    } else {
#pragma unroll 1
      for (int k = 31; k >= 0; k--){
        float dinv = __builtin_amdgcn_rcpf(Lt[wv][sl][k][k].x);
        float2 v = S32[k][c];
        v.x *= dinv; v.y *= dinv;
        S32[k][c] = v;
#pragma unroll 1
        for (int i = 0; i < k; i++){
          float2 l = Lt[wv][sl][i][k];
          float2 t2 = S32[i][c];
          t2.x -= l.x*v.x - l.y*v.y;
          t2.y -= l.x*v.y + l.y*v.x;
          S32[i][c] = t2;
        }
      }
    }
  }
  __syncthreads();
#pragma unroll
  for (int it2 = 0; it2 < 2; it2++){
    int ib = 2*wv + it2;
    bool upd = FWD ? (ib > jb) : (ib < jb);
    if (upd){
      const int off = it2*32;
#pragma unroll 2
      for (int k = 0; k < 32; k++){
        float2 b = S32[k][c];
#pragma unroll
        for (int i = 0; i < 32; i++){
          float2 l = Lt[wv][it2][i][k];
          s[off+i].x -= l.x*b.x - l.y*b.y;
          s[off+i].y -= l.x*b.y + l.y*b.x;
        }
      }
    }
  }
  if (wv == (jb >> 1)){
#pragma unroll
    for (int i = 0; i < 32; i++) s[LO + i] = S32[i][c];
  }
  __syncthreads();
}

__global__ __launch_bounds__(256, 2) void kSolve(const float2* __restrict__ Lg, float2* __restrict__ X,
                                                 const float* __restrict__ eb, int cf0){
  __shared__ __align__(16) float2 Lt[4][2][32][32];   // 64 KiB
  __shared__ float2 S32[32][64];                       // 16 KiB
  int fi = blockIdx.x;
  int f = cf0 + fi;
  const float2* Tf = Lg + (size_t)fi*TSTRIDE;
  float2* Xf = X + (size_t)f*CH*NB;
  int tid = threadIdx.x, wv = tid >> 6, c = tid & 63;
  float2 s[64];
#pragma unroll
  for (int i = 0; i < 64; i++) s[i] = Xf[(size_t)(wv*64 + i)*NB + c];
#pragma unroll 1
  for (int jp = 0; jp < 4; jp++){
    solvePhase<0,  true>(2*jp,     Tf, s, Lt, S32, wv, c);
    solvePhase<32, true>(2*jp + 1, Tf, s, Lt, S32, wv, c);
  }
#pragma unroll 1
  for (int jp = 3; jp >= 0; jp--){
    solvePhase<32, false>(2*jp + 1, Tf, s, Lt, S32, wv, c);
    solvePhase<0,  false>(2*jp,     Tf, s, Lt, S32, wv, c);
  }
  float te = 2.f * eb[f];
#pragma unroll
  for (int i = 0; i < 64; i++){
    float2 xv = Xf[(size_t)(wv*64 + i)*NB + c];
    float2 sv = s[i];
    Xf[(size_t)(wv*64 + i)*NB + c] = make_float2(te*sv.x - xv.x, te*sv.y - xv.y);
  }
}

// ---------------- inverse FFT stage 1: along ky (34 -> rows a=1..32) -------
__global__ __launch_bounds__(512) void kI1(const float2* __restrict__ X, float2* __restrict__ Y){
  __shared__ float pc[HW][NN], ps[HW][NN];
  int tid = threadIdx.x;
  for (int i = tid; i < HW*NN; i += 512){
    int a = i / NN, ky = i - a*NN;
    float s, c; sincosf(PI2*(float)(ky*(a+1))/34.f, &s, &c);
    pc[a][ky] = c; ps[a][ky] = s;
  }
  __syncthreads();
  int kx = blockIdx.x;
  int cc = (blockIdx.y << 3) + (tid >> 6);
  int b = tid & 63;
  float2 z[NN];
#pragma unroll
  for (int ky = 0; ky < NN; ky++) z[ky] = X[(((size_t)ky*NFH + kx)*CH + cc)*NB + b];
#pragma unroll 1
  for (int a = 0; a < HW; a++){
    float re = 0.f, im = 0.f;
#pragma unroll
    for (int ky = 0; ky < NN; ky++){
      float co = pc[a][ky], si = ps[a][ky];
      re += z[ky].x*co - z[ky].y*si;
      im += z[ky].x*si + z[ky].y*co;
    }
    Y[(((size_t)a*NFH + kx)*CH + cc)*NB + b] = make_float2(re, im);
  }
}

// ---------------- inverse FFT stage 2: along kx (18 -> real w=1..32) + bias
__global__ __launch_bounds__(256) void kI2(const float2* __restrict__ Y, const float* __restrict__ bias,
                                           float* __restrict__ out){
  __shared__ float tc[NFH][HW], tsn[NFH][HW];
  int tid = threadIdx.x;
  for (int i = tid; i < NFH*HW; i += 256){
    int kx = i >> 5, w = i & 31;
    float wt = (kx == 0 || kx == 17) ? (1.f/34.f) : (2.f/34.f);
    float s, c; sincosf(PI2*(float)(kx*(w+1))/34.f, &s, &c);
    tc[kx][w] = wt*c; tsn[kx][w] = wt*s;
  }
  __syncthreads();
  int cc = blockIdx.x;
  int a = (blockIdx.y << 2) + (tid >> 6);
  int b = tid & 63;
  float2 yv[NFH];
#pragma unroll
  for (int kx = 0; kx < NFH; kx++) yv[kx] = Y[(((size_t)a*NFH + kx)*CH + cc)*NB + b];
  float bi = bias[cc];
  float ov[HW];
#pragma unroll
  for (int w = 0; w < HW; w++){
    float acc = bi;
#pragma unroll
    for (int kx = 0; kx < NFH; kx++)
      acc += yv[kx].x*tc[kx][w] - yv[kx].y*tsn[kx][w];
    ov[w] = acc;
  }
  float4* op = (float4*)(out + (((size_t)b*CH + cc)*HW + a)*HW);
#pragma unroll
  for (int t = 0; t < 8; t++) op[t] = make_float4(ov[4*t], ov[4*t+1], ov[4*t+2], ov[4*t+3]);
}

extern "C" void kernel_launch(void* const* d_in, const int* in_sizes, int n_in,
                              void* d_out, int out_size, void* d_ws, size_t ws_size,
                              hipStream_t stream){
  (void)in_sizes; (void)n_in; (void)out_size;
  const float* x    = (const float*)d_in[0];
  const float* w    = (const float*)d_in[1];
  const float* bias = (const float*)d_in[2];
  float* out = (float*)d_out;
  char* ws = (char*)d_ws;

  const size_t X_BYTES  = (size_t)NFREQ*CH*NB*sizeof(float2);   // 80.2 MB
  const size_t WT_BYTES = (size_t)9*CH*CIN*sizeof(float);       // 2.35 MB
  const size_t C_BYTES  = (size_t)81*CH*CH*sizeof(float);       // 21.2 MB
  const size_t offX  = 0;
  const size_t offWT = offX + X_BYTES;
  const size_t offC  = offWT + WT_BYTES;
  const size_t offE  = offC + C_BYTES;
  const size_t offChunk = offE + 4096;
  const size_t perF = (size_t)TSTRIDE * sizeof(float2);          // 288 KB

  float2* X  = (float2*)(ws + offX);
  float*  wT = (float*)(ws + offWT);
  float*  C2 = (float*)(ws + offC);
  float*  eb = (float*)(ws + offE);
  float2* U  = (float2*)(ws + offChunk);
  float2* Mb = (float2*)(ws + offChunk);
  float2* Y  = (float2*)(ws + offChunk);

  size_t avail = ws_size > offChunk ? ws_size - offChunk : 0;
  int F = (int)(avail / perF);
  if (F < 1) F = 1;
  if (F > NFREQ) F = NFREQ;
  int nch = (NFREQ + F - 1) / F;
  F = (NFREQ + nch - 1) / nch;

  kF1<<<dim3(CH, 8), 256, 0, stream>>>(x, U);
  kF2<<<dim3(NFH, 32), 512, 0, stream>>>(U, X);
  kT0<<<(9*CH*CIN + 255)/256, 256, 0, stream>>>(w, wT);
  kC<<<dim3(81, 16), 256, 0, stream>>>(wT, C2);

  for (int cf0 = 0; cf0 < NFREQ; cf0 += F){
    int cF = (NFREQ - cf0 < F) ? (NFREQ - cf0) : F;
    kM<<<dim3(36, 32, (cF + 63) >> 6), 64, 0, stream>>>(C2, Mb, cf0, cF);
    kEps<<<cF, 256, 0, stream>>>(Mb, eb, cf0);
    for (int pb = 0; pb < 8; pb++){
      kPanel<<<cF, 256, 0, stream>>>(Mb, pb);
      int nrem = 7 - pb;
      int npairs = (nrem*(nrem+1)) >> 1;
      if (npairs > 0)
        kSyrk<<<dim3(cF, npairs), 256, 0, stream>>>(Mb, pb);
    }
    kSolve<<<cF, 256, 0, stream>>>(Mb, X, eb, cf0);
  }

  kI1<<<dim3(NFH, 32), 512, 0, stream>>>(X, Y);
  kI2<<<dim3(CH, 8), 256, 0, stream>>>(Y, bias, out);
}